// Round 9
// baseline (2931.550 us; speedup 1.0000x reference)
//
#include <hip/hip_runtime.h>
#include <hip/hip_cooperative_groups.h>
#include <cstddef>

namespace cg = cooperative_groups;

// Problem constants
#define N_NODES 50000
#define N_EDGES 800000
#define IN_DIM  128
#define EMB     32
#define ED      8
#define NLAYERS 4
#define NB      64
#define OUTD    10
#define EPS_BN  1e-5f

#define NODE_GRID 196    // scan chunks of 256 nodes
#define NT16      50000  // 800000/16
#define SREP 4           // stats replication; stage stride = SREP*64

typedef short bf16x8 __attribute__((ext_vector_type(8)));
typedef float f32x4  __attribute__((ext_vector_type(4)));

// ---------------- helpers ----------------

__device__ __forceinline__ unsigned short f2bf(float x) {
  union { float f; unsigned u; } v; v.f = x;
  unsigned b = v.u + 0x7FFFu + ((v.u >> 16) & 1u);
  return (unsigned short)(b >> 16);
}
__device__ __forceinline__ float bf2f(unsigned short s) {
  union { unsigned u; float f; } v; v.u = ((unsigned)s) << 16;
  return v.f;
}

__device__ __forceinline__ uint4 pack8_bf16(const float v[8]) {
  uint4 o;
  o.x = (unsigned)f2bf(v[0]) | ((unsigned)f2bf(v[1]) << 16);
  o.y = (unsigned)f2bf(v[2]) | ((unsigned)f2bf(v[3]) << 16);
  o.z = (unsigned)f2bf(v[4]) | ((unsigned)f2bf(v[5]) << 16);
  o.w = (unsigned)f2bf(v[6]) | ((unsigned)f2bf(v[7]) << 16);
  return o;
}

__device__ __forceinline__ void mac8_f4(float acc[8], const float4 v, const float* wk) {
#pragma unroll
  for (int j = 0; j < 8; ++j) acc[j] = fmaf(v.x, wk[j], acc[j]);
#pragma unroll
  for (int j = 0; j < 8; ++j) acc[j] = fmaf(v.y, wk[EMB + j], acc[j]);
#pragma unroll
  for (int j = 0; j < 8; ++j) acc[j] = fmaf(v.z, wk[2*EMB + j], acc[j]);
#pragma unroll
  for (int j = 0; j < 8; ++j) acc[j] = fmaf(v.w, wk[3*EMB + j], acc[j]);
}

struct KArgs {
  const float* x; const int* ei; const float* ea; const int* batch;
  const float *lin_in_w, *lin_in_b;
  const float *msg_w1, *msg_b1, *msg_g1, *msg_be1;
  const float *msg_w2, *msg_b2, *msg_g2, *msg_be2;
  const float *upd_w1, *upd_b1, *upd_g1, *upd_be1;
  const float *upd_w2, *upd_b2, *upd_g2, *upd_be2;
  const float *pred_w, *pred_b;
  unsigned short *y, *eap, *p, *q;
  float *h, *aggr, *z, *stats;
  int *cnt, *cnt2, *row_ptr, *bsum, *perm, *src_perm, *dst_perm;
  float* out;
};

// ---------------- the one kernel ----------------

__global__ __launch_bounds__(256, 4) void k_all(KArgs a)
{
  cg::grid_group grid = cg::this_grid();
  const int tid  = threadIdx.x;
  const int lane = tid & 63;
  const int wv   = tid >> 6;
  const int nblk = gridDim.x;

  __shared__ float lds_h[64][33];                       // node-stage h exchange
  __shared__ __align__(16) unsigned short lds_t[4][512]; // msg2 repack
  __shared__ float lds_s4[4][32], lds_q4[4][32];        // msg2 stats
  __shared__ float lds_ws_s[32], lds_ws_q[32];          // wave-stats
  __shared__ float sred[256];                           // block-stats / pool
  __shared__ float cf[64];                              // BN coefs
  __shared__ int   sscan[256];                          // scans
  __shared__ float hg[EMB];                             // pool

  const float invE = 1.0f / (float)N_EDGES;
  const float invN = 1.0f / (float)N_NODES;

  // ============ stage 0: lin_in + p/q(layer0), and histogram ============
  for (int n0 = blockIdx.x*64; n0 < N_NODES; n0 += nblk*64) {
    const int n  = n0 + lane;
    const int c0 = wv*8;
    if (n < N_NODES) {
      float acc[8];
#pragma unroll
      for (int j = 0; j < 8; ++j) acc[j] = a.lin_in_b[c0 + j];
      const float4* xp = (const float4*)(a.x + (size_t)n*IN_DIM);
#pragma unroll 8
      for (int k4 = 0; k4 < IN_DIM/4; ++k4)
        mac8_f4(acc, xp[k4], a.lin_in_w + (k4*4)*EMB + c0);
      float4 o0, o1;
      o0.x = acc[0]; o0.y = acc[1]; o0.z = acc[2]; o0.w = acc[3];
      o1.x = acc[4]; o1.y = acc[5]; o1.z = acc[6]; o1.w = acc[7];
      *(float4*)(a.h + (size_t)n*EMB + c0)     = o0;
      *(float4*)(a.h + (size_t)n*EMB + c0 + 4) = o1;
#pragma unroll
      for (int j = 0; j < 8; ++j) lds_h[lane][c0 + j] = acc[j];
    }
    __syncthreads();
    if (n < N_NODES) {
      float ap[8], aq[8];
#pragma unroll
      for (int j = 0; j < 8; ++j) { ap[j] = a.msg_b1[c0 + j]; aq[j] = 0.f; }
#pragma unroll
      for (int k = 0; k < EMB; ++k) {
        const float hv = lds_h[lane][k];
        const float* wp = a.msg_w1 + k*EMB + c0;
        const float* wq = a.msg_w1 + (EMB + k)*EMB + c0;
#pragma unroll
        for (int j = 0; j < 8; ++j) ap[j] = fmaf(hv, wp[j], ap[j]);
#pragma unroll
        for (int j = 0; j < 8; ++j) aq[j] = fmaf(hv, wq[j], aq[j]);
      }
      *(uint4*)(a.p + (size_t)n*EMB + c0) = pack8_bf16(ap);
      *(uint4*)(a.q + (size_t)n*EMB + c0) = pack8_bf16(aq);
    }
    __syncthreads();
  }
  for (int e = blockIdx.x*256 + tid; e < N_EDGES; e += nblk*256)
    atomicAdd(&a.cnt[a.ei[N_EDGES + e]], 1);
  grid.sync();

  // ============ stage 1: scan A (per-256-node chunk) ============
  for (int blk = blockIdx.x; blk < NODE_GRID; blk += nblk) {
    const int gid = blk*256 + tid;
    const int v = (gid < N_NODES) ? a.cnt[gid] : 0;
    sscan[tid] = v;
    __syncthreads();
    for (int o = 1; o < 256; o <<= 1) {
      const int t = (tid >= o) ? sscan[tid - o] : 0;
      __syncthreads();
      sscan[tid] += t;
      __syncthreads();
    }
    if (gid < N_NODES) a.row_ptr[gid] = sscan[tid] - v;
    if (tid == 255) a.bsum[blk] = sscan[255];
    __syncthreads();
  }
  grid.sync();

  // ============ stage 2: scan B (block 0) ============
  if (blockIdx.x == 0) {
    const int v = (tid < NODE_GRID) ? a.bsum[tid] : 0;
    sscan[tid] = v;
    __syncthreads();
    for (int o = 1; o < 256; o <<= 1) {
      const int t = (tid >= o) ? sscan[tid - o] : 0;
      __syncthreads();
      sscan[tid] += t;
      __syncthreads();
    }
    if (tid < NODE_GRID) a.bsum[tid] = sscan[tid] - v;
    if (tid == 0) a.row_ptr[N_NODES] = N_EDGES;
  }
  grid.sync();

  // ============ stage 3: scan C ============
  for (int gid = blockIdx.x*256 + tid; gid < N_NODES; gid += nblk*256)
    a.row_ptr[gid] += a.bsum[gid >> 8];
  grid.sync();

  // ============ stage 4: place ============
  for (int e = blockIdx.x*256 + tid; e < N_EDGES; e += nblk*256) {
    const int d = a.ei[N_EDGES + e];
    const int pos = a.row_ptr[d] + atomicAdd(&a.cnt2[d], 1);
    a.perm[pos] = e;
  }
  grid.sync();

  // ============ stage 5: permute edge data ============
  for (int i = blockIdx.x*256 + tid; i < N_EDGES; i += nblk*256) {
    const int e = a.perm[i];
    a.src_perm[i] = a.ei[e];
    a.dst_perm[i] = a.ei[N_EDGES + e];
    const float4* src4 = (const float4*)(a.ea + (size_t)e*ED);
    const float4 v0 = src4[0], v1 = src4[1];
    const float ev[8] = {v0.x, v0.y, v0.z, v0.w, v1.x, v1.y, v1.z, v1.w};
    unsigned u[4];
#pragma unroll
    for (int j = 0; j < 4; ++j)
      u[j] = (unsigned)f2bf(ev[2*j]) | ((unsigned)f2bf(ev[2*j+1]) << 16);
    uint4 o; o.x = u[0]; o.y = u[1]; o.z = u[2]; o.w = u[3];
    *(uint4*)(a.eap + (size_t)i*ED) = o;
  }
  grid.sync();

  // ============ layers ============
  for (int l = 0; l < NLAYERS; ++l) {
    const int st = l*4;
    const float* w1b = a.msg_w1 + (size_t)l*(2*EMB+ED)*EMB + (size_t)2*EMB*EMB;
    const float* w2  = a.msg_w2 + (size_t)l*EMB*EMB;
    const float* uw1 = a.upd_w1 + (size_t)l*(2*EMB)*EMB;
    const float* uw2 = a.upd_w2 + (size_t)l*EMB*EMB;
    float* st0 = a.stats + (size_t)st*SREP*64;
    float* st1 = a.stats + (size_t)(st+1)*SREP*64;
    float* st2 = a.stats + (size_t)(st+2)*SREP*64;
    float* st3 = a.stats + (size_t)(st+3)*SREP*64;

    // ---- msg1: y1 = p[dst]+q[src]+ea@w1b ; bf16 store; stats ----
    {
      float ts[EMB], tss[EMB];
#pragma unroll
      for (int c = 0; c < EMB; ++c) { ts[c] = 0.f; tss[c] = 0.f; }
      for (int i = blockIdx.x*256 + tid; i < N_EDGES; i += nblk*256) {
        const int dst = a.dst_perm[i];
        const int src = a.src_perm[i];
        float acc[EMB];
        const uint4* pd = (const uint4*)(a.p + (size_t)dst*EMB);
        const uint4* qs = (const uint4*)(a.q + (size_t)src*EMB);
#pragma unroll
        for (int j4 = 0; j4 < 4; ++j4) {
          const uint4 av = pd[j4];
          const uint4 bv = qs[j4];
          const unsigned ua[4] = {av.x, av.y, av.z, av.w};
          const unsigned ub[4] = {bv.x, bv.y, bv.z, bv.w};
#pragma unroll
          for (int t = 0; t < 4; ++t) {
            acc[j4*8 + 2*t]   = bf2f((unsigned short)(ua[t] & 0xFFFFu)) +
                                bf2f((unsigned short)(ub[t] & 0xFFFFu));
            acc[j4*8 + 2*t+1] = bf2f((unsigned short)(ua[t] >> 16)) +
                                bf2f((unsigned short)(ub[t] >> 16));
          }
        }
        const uint4 eraw = *(const uint4*)(a.eap + (size_t)i*ED);
        const unsigned ue[4] = {eraw.x, eraw.y, eraw.z, eraw.w};
        float ev[8];
#pragma unroll
        for (int t = 0; t < 4; ++t) {
          ev[2*t]   = bf2f((unsigned short)(ue[t] & 0xFFFFu));
          ev[2*t+1] = bf2f((unsigned short)(ue[t] >> 16));
        }
#pragma unroll
        for (int k = 0; k < 8; ++k) {
          const float* wk = w1b + k*EMB;
#pragma unroll
          for (int c = 0; c < EMB; ++c) acc[c] = fmaf(ev[k], wk[c], acc[c]);
        }
        unsigned short us[EMB];
#pragma unroll
        for (int c = 0; c < EMB; ++c) us[c] = f2bf(acc[c]);
        unsigned u[16];
#pragma unroll
        for (int j = 0; j < 16; ++j)
          u[j] = (unsigned)us[2*j] | ((unsigned)us[2*j+1] << 16);
        uint4* dp = (uint4*)(a.y + (size_t)i*EMB);
#pragma unroll
        for (int j = 0; j < 4; ++j) {
          uint4 o; o.x = u[4*j]; o.y = u[4*j+1]; o.z = u[4*j+2]; o.w = u[4*j+3];
          dp[j] = o;
        }
#pragma unroll
        for (int c = 0; c < EMB; ++c) {
          const float v = bf2f(us[c]);
          ts[c] += v;
          tss[c] = fmaf(v, v, tss[c]);
        }
      }
      // block stats -> atomics
#pragma unroll
      for (int c = 0; c < EMB; ++c) {
        float aa = ts[c];
        float qq = tss[c];
#pragma unroll
        for (int o = 32; o > 0; o >>= 1) {
          aa += __shfl_down(aa, o, 64);
          qq += __shfl_down(qq, o, 64);
        }
        if (lane == 0) { sred[wv*64 + c] = aa; sred[wv*64 + EMB + c] = qq; }
      }
      __syncthreads();
      if (tid < 64) {
        const float v = sred[tid] + sred[64 + tid] + sred[128 + tid] + sred[192 + tid];
        atomicAdd(st0 + ((blockIdx.x & (SREP-1)) << 6) + tid, v);
      }
      __syncthreads();
    }
    grid.sync();

    // ---- msg2 (MFMA): y2 = relu(bn1(y1)) @ W2 + b2, in place; stats ----
    {
      if (tid < EMB) {
        float s = 0.f, ss = 0.f;
#pragma unroll
        for (int r = 0; r < SREP; ++r) { s += st0[r*64 + tid]; ss += st0[r*64 + EMB + tid]; }
        const float mu  = s * invE;
        const float var = ss * invE - mu*mu;
        const float aa = a.msg_g1[l*EMB + tid] * rsqrtf(var + EPS_BN);
        cf[tid] = aa;
        cf[EMB + tid] = fmaf(-mu, aa, a.msg_be1[l*EMB + tid]);
      }
      __syncthreads();

      const int n0i = lane & 15;
      const int kb  = lane >> 4;
      bf16x8 Blo, Bhi;
#pragma unroll
      for (int j = 0; j < 8; ++j) {
        Blo[j] = (short)f2bf(w2[(kb*8 + j)*EMB + n0i]);
        Bhi[j] = (short)f2bf(w2[(kb*8 + j)*EMB + 16 + n0i]);
      }
      float a1[8], c1[8];
#pragma unroll
      for (int j = 0; j < 8; ++j) {
        a1[j] = cf[kb*8 + j];
        c1[j] = cf[EMB + kb*8 + j];
      }
      const float b2c0 = a.msg_b2[l*EMB + n0i], b2c1 = a.msg_b2[l*EMB + 16 + n0i];

      float ts8[8], tss8[8];
#pragma unroll
      for (int j = 0; j < 8; ++j) { ts8[j] = 0.f; tss8[j] = 0.f; }

      for (int tile = blockIdx.x*4 + wv; tile < NT16; tile += nblk*4) {
        const size_t e0 = (size_t)tile * 16;
        const uint4 araw = *(const uint4*)(a.y + (e0 + n0i)*EMB + kb*8);
        unsigned int ua[4] = {araw.x, araw.y, araw.z, araw.w};
        bf16x8 A;
#pragma unroll
        for (int j = 0; j < 4; ++j) {
          float v0 = bf2f((unsigned short)(ua[j] & 0xFFFFu));
          float v1 = bf2f((unsigned short)(ua[j] >> 16));
          v0 = fmaxf(fmaf(a1[2*j],   v0, c1[2*j]),   0.f);
          v1 = fmaxf(fmaf(a1[2*j+1], v1, c1[2*j+1]), 0.f);
          A[2*j]   = (short)f2bf(v0);
          A[2*j+1] = (short)f2bf(v1);
        }
        f32x4 acc0 = {0.f, 0.f, 0.f, 0.f};
        f32x4 acc1 = {0.f, 0.f, 0.f, 0.f};
        acc0 = __builtin_amdgcn_mfma_f32_16x16x32_bf16(A, Blo, acc0, 0, 0, 0);
        acc1 = __builtin_amdgcn_mfma_f32_16x16x32_bf16(A, Bhi, acc1, 0, 0, 0);
#pragma unroll
        for (int r = 0; r < 4; ++r) {
          const int row = kb*4 + r;
          lds_t[wv][row*32 + n0i]      = f2bf(acc0[r] + b2c0);
          lds_t[wv][row*32 + 16 + n0i] = f2bf(acc1[r] + b2c1);
        }
        const uint4 orow = *(const uint4*)&lds_t[wv][(lane>>2)*32 + (lane&3)*8];
        *(uint4*)(a.y + (e0 + (lane>>2))*EMB + (lane&3)*8) = orow;
        unsigned int uo[4] = {orow.x, orow.y, orow.z, orow.w};
#pragma unroll
        for (int j = 0; j < 4; ++j) {
          const float v0 = bf2f((unsigned short)(uo[j] & 0xFFFFu));
          const float v1 = bf2f((unsigned short)(uo[j] >> 16));
          ts8[2*j]   += v0;  tss8[2*j]   = fmaf(v0, v0, tss8[2*j]);
          ts8[2*j+1] += v1;  tss8[2*j+1] = fmaf(v1, v1, tss8[2*j+1]);
        }
      }
#pragma unroll
      for (int j = 0; j < 8; ++j) {
        float s = ts8[j], qq = tss8[j];
#pragma unroll
        for (int o = 4; o < 64; o <<= 1) {
          s  += __shfl_xor(s, o, 64);
          qq += __shfl_xor(qq, o, 64);
        }
        ts8[j] = s; tss8[j] = qq;
      }
      if (lane < 4) {
#pragma unroll
        for (int j = 0; j < 8; ++j) {
          lds_s4[wv][lane*8 + j] = ts8[j];
          lds_q4[wv][lane*8 + j] = tss8[j];
        }
      }
      __syncthreads();
      if (tid < 64) {
        const int c = tid & 31;
        const int kind = tid >> 5;
        float v = 0.f;
#pragma unroll
        for (int wq = 0; wq < 4; ++wq)
          v += kind ? lds_q4[wq][c] : lds_s4[wq][c];
        atomicAdd(st1 + ((blockIdx.x & (SREP-1)) << 6) + kind*32 + c, v);
      }
      __syncthreads();
    }
    grid.sync();

    // ---- aggr: CSR gather with bn2+relu ----
    {
      if (tid < EMB) {
        float s = 0.f, ss = 0.f;
#pragma unroll
        for (int r = 0; r < SREP; ++r) { s += st1[r*64 + tid]; ss += st1[r*64 + EMB + tid]; }
        const float mu  = s * invE;
        const float var = ss * invE - mu*mu;
        const float aa = a.msg_g2[l*EMB + tid] * rsqrtf(var + EPS_BN);
        cf[tid] = aa;
        cf[EMB + tid] = fmaf(-mu, aa, a.msg_be2[l*EMB + tid]);
      }
      __syncthreads();

      const int grp = tid >> 5;
      const int ll  = tid & 31;
      const int rof = ll >> 4;
      const int cp  = ll & 15;
      const float a0 = cf[2*cp],     b0 = cf[EMB + 2*cp];
      const float a1c = cf[2*cp + 1], b1c = cf[EMB + 2*cp + 1];
      for (int n = blockIdx.x*8 + grp; n < N_NODES; n += nblk*8) {
        const int lo = a.row_ptr[n], hi = a.row_ptr[n+1];
        float s0 = 0.f, s1 = 0.f;
        for (int i = lo + rof; i < hi; i += 2) {
          const unsigned u = *(const unsigned*)(a.y + (size_t)i*EMB + 2*cp);
          const float v0 = bf2f((unsigned short)(u & 0xFFFFu));
          const float v1 = bf2f((unsigned short)(u >> 16));
          s0 += fmaxf(fmaf(a0, v0, b0), 0.f);
          s1 += fmaxf(fmaf(a1c, v1, b1c), 0.f);
        }
        s0 += __shfl_xor(s0, 16, 64);
        s1 += __shfl_xor(s1, 16, 64);
        if (rof == 0) {
          float2 o; o.x = s0; o.y = s1;
          *(float2*)(a.aggr + (size_t)n*EMB + 2*cp) = o;
        }
      }
      __syncthreads();
    }
    grid.sync();

    // ---- upd1: z = concat(h, aggr) @ uw1 + b ; stats ----
    {
      const int c0 = wv*8;
      float ts8[8], tss8[8];
#pragma unroll
      for (int j = 0; j < 8; ++j) { ts8[j] = 0.f; tss8[j] = 0.f; }
      for (int nb0 = blockIdx.x*64; nb0 < N_NODES; nb0 += nblk*64) {
        const int n = nb0 + lane;
        float acc[8];
#pragma unroll
        for (int j = 0; j < 8; ++j) acc[j] = 0.f;
        if (n < N_NODES) {
#pragma unroll
          for (int j = 0; j < 8; ++j) acc[j] = a.upd_b1[l*EMB + c0 + j];
          const float4* hp = (const float4*)(a.h + (size_t)n*EMB);
          const float4* ap = (const float4*)(a.aggr + (size_t)n*EMB);
#pragma unroll
          for (int k4 = 0; k4 < 8; ++k4) mac8_f4(acc, hp[k4], uw1 + (k4*4)*EMB + c0);
#pragma unroll
          for (int k4 = 0; k4 < 8; ++k4) mac8_f4(acc, ap[k4], uw1 + (EMB + k4*4)*EMB + c0);
          float4 o0, o1;
          o0.x = acc[0]; o0.y = acc[1]; o0.z = acc[2]; o0.w = acc[3];
          o1.x = acc[4]; o1.y = acc[5]; o1.z = acc[6]; o1.w = acc[7];
          *(float4*)(a.z + (size_t)n*EMB + c0)     = o0;
          *(float4*)(a.z + (size_t)n*EMB + c0 + 4) = o1;
        }
#pragma unroll
        for (int j = 0; j < 8; ++j) { ts8[j] += acc[j]; tss8[j] = fmaf(acc[j], acc[j], tss8[j]); }
      }
#pragma unroll
      for (int j = 0; j < 8; ++j) {
        float aa = ts8[j], bb = tss8[j];
#pragma unroll
        for (int o = 32; o > 0; o >>= 1) {
          aa += __shfl_down(aa, o, 64);
          bb += __shfl_down(bb, o, 64);
        }
        ts8[j] = aa; tss8[j] = bb;
      }
      if (lane == 0) {
#pragma unroll
        for (int j = 0; j < 8; ++j) { lds_ws_s[wv*8 + j] = ts8[j]; lds_ws_q[wv*8 + j] = tss8[j]; }
      }
      __syncthreads();
      if (tid < 64) {
        const float v = (tid < 32) ? lds_ws_s[tid] : lds_ws_q[tid - 32];
        atomicAdd(st2 + ((blockIdx.x & (SREP-1)) << 6) + tid, v);
      }
      __syncthreads();
    }
    grid.sync();

    // ---- upd2: aggr = relu(bn(z)) @ uw2 + b ; stats ----
    {
      if (tid < EMB) {
        float s = 0.f, ss = 0.f;
#pragma unroll
        for (int r = 0; r < SREP; ++r) { s += st2[r*64 + tid]; ss += st2[r*64 + EMB + tid]; }
        const float mu  = s * invN;
        const float var = ss * invN - mu*mu;
        const float aa = a.upd_g1[l*EMB + tid] * rsqrtf(var + EPS_BN);
        cf[tid] = aa;
        cf[EMB + tid] = fmaf(-mu, aa, a.upd_be1[l*EMB + tid]);
      }
      __syncthreads();

      const int c0 = wv*8;
      float ts8[8], tss8[8];
#pragma unroll
      for (int j = 0; j < 8; ++j) { ts8[j] = 0.f; tss8[j] = 0.f; }
      for (int nb0 = blockIdx.x*64; nb0 < N_NODES; nb0 += nblk*64) {
        const int n = nb0 + lane;
        float acc[8];
#pragma unroll
        for (int j = 0; j < 8; ++j) acc[j] = 0.f;
        if (n < N_NODES) {
#pragma unroll
          for (int j = 0; j < 8; ++j) acc[j] = a.upd_b2[l*EMB + c0 + j];
          const float4* zp = (const float4*)(a.z + (size_t)n*EMB);
#pragma unroll
          for (int k4 = 0; k4 < 8; ++k4) {
            const float4 v = zp[k4];
            const float mv[4] = {v.x, v.y, v.z, v.w};
#pragma unroll
            for (int t = 0; t < 4; ++t) {
              const int k = 4*k4 + t;
              const float m = fmaxf(fmaf(cf[k], mv[t], cf[EMB + k]), 0.f);
              const float* wk = uw2 + k*EMB + c0;
#pragma unroll
              for (int j = 0; j < 8; ++j) acc[j] = fmaf(m, wk[j], acc[j]);
            }
          }
          float4 o0, o1;
          o0.x = acc[0]; o0.y = acc[1]; o0.z = acc[2]; o0.w = acc[3];
          o1.x = acc[4]; o1.y = acc[5]; o1.z = acc[6]; o1.w = acc[7];
          *(float4*)(a.aggr + (size_t)n*EMB + c0)     = o0;
          *(float4*)(a.aggr + (size_t)n*EMB + c0 + 4) = o1;
        }
#pragma unroll
        for (int j = 0; j < 8; ++j) { ts8[j] += acc[j]; tss8[j] = fmaf(acc[j], acc[j], tss8[j]); }
      }
#pragma unroll
      for (int j = 0; j < 8; ++j) {
        float aa = ts8[j], bb = tss8[j];
#pragma unroll
        for (int o = 32; o > 0; o >>= 1) {
          aa += __shfl_down(aa, o, 64);
          bb += __shfl_down(bb, o, 64);
        }
        ts8[j] = aa; tss8[j] = bb;
      }
      if (lane == 0) {
#pragma unroll
        for (int j = 0; j < 8; ++j) { lds_ws_s[wv*8 + j] = ts8[j]; lds_ws_q[wv*8 + j] = tss8[j]; }
      }
      __syncthreads();
      if (tid < 64) {
        const float v = (tid < 32) ? lds_ws_s[tid] : lds_ws_q[tid - 32];
        atomicAdd(st3 + ((blockIdx.x & (SREP-1)) << 6) + tid, v);
      }
      __syncthreads();
    }
    grid.sync();

    // ---- resid: h += relu(bn(aggr)); p/q for next layer ----
    {
      if (tid < EMB) {
        float s = 0.f, ss = 0.f;
#pragma unroll
        for (int r = 0; r < SREP; ++r) { s += st3[r*64 + tid]; ss += st3[r*64 + EMB + tid]; }
        const float mu  = s * invN;
        const float var = ss * invN - mu*mu;
        const float aa = a.upd_g2[l*EMB + tid] * rsqrtf(var + EPS_BN);
        cf[tid] = aa;
        cf[EMB + tid] = fmaf(-mu, aa, a.upd_be2[l*EMB + tid]);
      }
      __syncthreads();

      const float* w1n = (l+1 < NLAYERS) ? a.msg_w1 + (size_t)(l+1)*(2*EMB+ED)*EMB : nullptr;
      const float* b1n = (l+1 < NLAYERS) ? a.msg_b1 + (size_t)(l+1)*EMB : nullptr;
      const int c0 = wv*8;
      for (int nb0 = blockIdx.x*64; nb0 < N_NODES; nb0 += nblk*64) {
        const int n = nb0 + lane;
        if (n < N_NODES) {
          const float4* zp = (const float4*)(a.aggr + (size_t)n*EMB + c0);
          float4* hp = (float4*)(a.h + (size_t)n*EMB + c0);
          float hn[8];
          const float4 z0 = zp[0], z1 = zp[1];
          const float4 h0 = hp[0], h1 = hp[1];
          const float zv[8] = {z0.x, z0.y, z0.z, z0.w, z1.x, z1.y, z1.z, z1.w};
          const float hv[8] = {h0.x, h0.y, h0.z, h0.w, h1.x, h1.y, h1.z, h1.w};
#pragma unroll
          for (int j = 0; j < 8; ++j) {
            const int k = c0 + j;
            hn[j] = hv[j] + fmaxf(fmaf(cf[k], zv[j], cf[EMB + k]), 0.f);
            lds_h[lane][k] = hn[j];
          }
          float4 o0, o1;
          o0.x = hn[0]; o0.y = hn[1]; o0.z = hn[2]; o0.w = hn[3];
          o1.x = hn[4]; o1.y = hn[5]; o1.z = hn[6]; o1.w = hn[7];
          hp[0] = o0; hp[1] = o1;
        }
        __syncthreads();
        if (n < N_NODES && w1n) {
          float ap[8], aq[8];
#pragma unroll
          for (int j = 0; j < 8; ++j) { ap[j] = b1n[c0 + j]; aq[j] = 0.f; }
#pragma unroll
          for (int k = 0; k < EMB; ++k) {
            const float hvv = lds_h[lane][k];
            const float* wp = w1n + k*EMB + c0;
            const float* wq = w1n + (EMB + k)*EMB + c0;
#pragma unroll
            for (int j = 0; j < 8; ++j) ap[j] = fmaf(hvv, wp[j], ap[j]);
#pragma unroll
            for (int j = 0; j < 8; ++j) aq[j] = fmaf(hvv, wq[j], aq[j]);
          }
          *(uint4*)(a.p + (size_t)n*EMB + c0) = pack8_bf16(ap);
          *(uint4*)(a.q + (size_t)n*EMB + c0) = pack8_bf16(aq);
        }
        __syncthreads();
      }
    }
    grid.sync();
  } // layers

  // ============ pool + head ============
  for (int b = blockIdx.x; b < NB; b += nblk) {
    int lo = 0, hi = N_NODES;
    while (lo < hi) { int m = (lo + hi) >> 1; if (a.batch[m] < b) lo = m + 1; else hi = m; }
    const int start = lo;
    hi = N_NODES;
    while (lo < hi) { int m = (lo + hi) >> 1; if (a.batch[m] < b + 1) lo = m + 1; else hi = m; }
    const int end = lo;

    const int c = tid & (EMB-1);
    const int r = tid >> 5;
    float s = 0.f;
    for (int n = start + r; n < end; n += 8) s += a.h[(size_t)n*EMB + c];
    sred[tid] = s;
    __syncthreads();
    if (tid < EMB) {
      float tot = 0.f;
#pragma unroll
      for (int r2 = 0; r2 < 8; ++r2) tot += sred[r2*EMB + tid];
      const float cnt = (float)(end - start);
      hg[tid] = tot / fmaxf(cnt, 1.f);
    }
    __syncthreads();
    if (tid < OUTD) {
      float acc = a.pred_b[tid];
#pragma unroll
      for (int cc = 0; cc < EMB; ++cc) acc = fmaf(hg[cc], a.pred_w[cc*OUTD + tid], acc);
      a.out[b*OUTD + tid] = acc;
    }
    __syncthreads();
  }
}

// ---------------- host ----------------

extern "C" void kernel_launch(void* const* d_in, const int* in_sizes, int n_in,
                              void* d_out, int out_size, void* d_ws, size_t ws_size,
                              hipStream_t stream) {
  KArgs a;
  a.x        = (const float*)d_in[0];
  a.ei       = (const int*)  d_in[1];
  a.ea       = (const float*)d_in[2];
  a.batch    = (const int*)  d_in[3];
  a.lin_in_w = (const float*)d_in[4];
  a.lin_in_b = (const float*)d_in[5];
  a.msg_w1   = (const float*)d_in[6];
  a.msg_b1   = (const float*)d_in[7];
  a.msg_g1   = (const float*)d_in[8];
  a.msg_be1  = (const float*)d_in[9];
  a.msg_w2   = (const float*)d_in[10];
  a.msg_b2   = (const float*)d_in[11];
  a.msg_g2   = (const float*)d_in[12];
  a.msg_be2  = (const float*)d_in[13];
  a.upd_w1   = (const float*)d_in[14];
  a.upd_b1   = (const float*)d_in[15];
  a.upd_g1   = (const float*)d_in[16];
  a.upd_be1  = (const float*)d_in[17];
  a.upd_w2   = (const float*)d_in[18];
  a.upd_b2   = (const float*)d_in[19];
  a.upd_g2   = (const float*)d_in[20];
  a.upd_be2  = (const float*)d_in[21];
  a.pred_w   = (const float*)d_in[22];
  a.pred_b   = (const float*)d_in[23];
  a.out      = (float*)d_out;

  char* wsb = (char*)d_ws;
  a.y   = (unsigned short*)wsb;                                   // E*32 bf16
  a.eap = (unsigned short*)(wsb + (size_t)N_EDGES*EMB*2);         // E*8 bf16
  a.p   = a.eap + (size_t)N_EDGES*ED;                             // N*32 bf16
  a.q   = a.p + (size_t)N_NODES*EMB;                              // N*32 bf16
  a.h     = (float*)(a.q + (size_t)N_NODES*EMB);                  // N*32 f32
  a.aggr  = a.h + (size_t)N_NODES*EMB;                            // N*32 f32
  a.z     = a.aggr + (size_t)N_NODES*EMB;                         // N*32 f32
  a.stats = a.z + (size_t)N_NODES*EMB;                            // 16 x SREP x 64
  a.cnt     = (int*)(a.stats + 16*SREP*64);
  a.cnt2    = a.cnt + N_NODES;
  a.row_ptr = a.cnt2 + N_NODES;
  a.bsum    = a.row_ptr + N_NODES + 1;
  a.perm    = a.bsum + 256;
  a.src_perm= a.perm + N_EDGES;
  a.dst_perm= a.src_perm + N_EDGES;
  const size_t need = ((size_t)((char*)(a.dst_perm + N_EDGES) - wsb));
  if (ws_size < need) return;

  hipMemsetAsync(a.stats, 0, (16*SREP*64 + 2*N_NODES)*sizeof(float), stream);

  int occ = 0;
  hipOccupancyMaxActiveBlocksPerMultiprocessor(&occ, (const void*)k_all, 256, 0);
  if (occ < 1) occ = 1;
  int grid = occ * 256;
  if (grid > 1024) grid = 1024;
  void* kargs[] = { (void*)&a };
  hipLaunchCooperativeKernel((const void*)k_all, dim3(grid), dim3(256), kargs, 0, stream);
}

// Round 10
// 883.928 us; speedup vs baseline: 3.3165x; 3.3165x over previous
//
#include <hip/hip_runtime.h>
#include <cstddef>

// Problem constants
#define N_NODES 50000
#define N_EDGES 800000
#define IN_DIM  128
#define EMB     32
#define ED      8
#define NLAYERS 4
#define NB      64
#define OUTD    10
#define EPS_BN  1e-5f

#define EDGE_GRID 3125   // 800000/256 exact
#define NODE_GRID 196    // ceil(50000/256)  (scan kernels)
#define NODE4_GRID 782   // ceil(50000/64)   (4-wave node kernels)
#define AU_GRID   6250   // 50000/8 (aggr+upd1)
#define MSG1_EPT  2
#define MSG1_GRID 1563   // ceil(800000/512)
#define NT16      50000  // 800000/16
#define NTILE_N   3125   // 50000/16 (lin_in tiles)
#define LIN_GRID  782    // ceil(3125/4)
#define MSG2_TPW  16
#define MSG2_GRID 782

#define SREP 4           // stats replication; stage stride = SREP*64

typedef short bf16x8 __attribute__((ext_vector_type(8)));
typedef float f32x4  __attribute__((ext_vector_type(4)));

// ---------------- helpers ----------------

__device__ __forceinline__ unsigned short f2bf(float x) {
  union { float f; unsigned u; } v; v.f = x;
  unsigned b = v.u + 0x7FFFu + ((v.u >> 16) & 1u);
  return (unsigned short)(b >> 16);
}
__device__ __forceinline__ float bf2f(unsigned short s) {
  union { unsigned u; float f; } v; v.u = ((unsigned)s) << 16;
  return v.f;
}

// Inline BN-coef preamble from SREP-replicated stats: cf[c]=a, cf[32+c]=be-mu*a.
__device__ __forceinline__ void coef_from_stats(const float* __restrict__ stats_stage,
                                                const float* __restrict__ g,
                                                const float* __restrict__ be,
                                                float inv_count, float* __restrict__ cf) {
  if (threadIdx.x < EMB) {
    const int c = threadIdx.x;
    float s = 0.f, ss = 0.f;
#pragma unroll
    for (int r = 0; r < SREP; ++r) {
      s  += stats_stage[r*64 + c];
      ss += stats_stage[r*64 + EMB + c];
    }
    const float mu  = s * inv_count;
    const float var = ss * inv_count - mu*mu;
    const float a = g[c] * rsqrtf(var + EPS_BN);
    cf[c] = a;
    cf[EMB + c] = fmaf(-mu, a, be[c]);
  }
  __syncthreads();
}

// 256-thread block stats (per-thread sum/sumsq over 32 cols) -> 64 atomics.
__device__ __forceinline__ void block_stats_atomic(const float ts[EMB], const float tss[EMB],
                                                   float* __restrict__ stats_stage) {
  __shared__ float sred[256];
  const int lane = threadIdx.x & 63;
  const int wid  = threadIdx.x >> 6;
#pragma unroll
  for (int c = 0; c < EMB; ++c) {
    float a = ts[c];
    float q = tss[c];
#pragma unroll
    for (int o = 32; o > 0; o >>= 1) {
      a += __shfl_down(a, o, 64);
      q += __shfl_down(q, o, 64);
    }
    if (lane == 0) { sred[wid*64 + c] = a; sred[wid*64 + EMB + c] = q; }
  }
  __syncthreads();
  if (threadIdx.x < 64) {
    const float v = sred[threadIdx.x] + sred[64 + threadIdx.x] +
                    sred[128 + threadIdx.x] + sred[192 + threadIdx.x];
    atomicAdd(stats_stage + ((blockIdx.x & (SREP-1)) << 6) + threadIdx.x, v);
  }
}

// Per-wave stats (8 cols each, node kernels) -> LDS -> 64 atomics; has a barrier.
__device__ __forceinline__ void wave_stats_atomic(float ts[8], float tss[8],
                                                  float* __restrict__ lds_s,
                                                  float* __restrict__ lds_q,
                                                  float* __restrict__ stats_stage) {
  const int lane = threadIdx.x & 63;
  const int wv   = threadIdx.x >> 6;
#pragma unroll
  for (int j = 0; j < 8; ++j) {
    float a = ts[j], b = tss[j];
#pragma unroll
    for (int o = 32; o > 0; o >>= 1) {
      a += __shfl_down(a, o, 64);
      b += __shfl_down(b, o, 64);
    }
    ts[j] = a; tss[j] = b;
  }
  if (lane == 0) {
#pragma unroll
    for (int j = 0; j < 8; ++j) {
      lds_s[wv*8 + j] = ts[j];
      lds_q[wv*8 + j] = tss[j];
    }
  }
  __syncthreads();
  if (threadIdx.x < 64) {
    const float v = (threadIdx.x < 32) ? lds_s[threadIdx.x] : lds_q[threadIdx.x - 32];
    atomicAdd(stats_stage + ((blockIdx.x & (SREP-1)) << 6) + threadIdx.x, v);
  }
}

__device__ __forceinline__ void mac8_f4(float acc[8], const float4 v, const float* wk) {
#pragma unroll
  for (int j = 0; j < 8; ++j) acc[j] = fmaf(v.x, wk[j], acc[j]);
#pragma unroll
  for (int j = 0; j < 8; ++j) acc[j] = fmaf(v.y, wk[EMB + j], acc[j]);
#pragma unroll
  for (int j = 0; j < 8; ++j) acc[j] = fmaf(v.z, wk[2*EMB + j], acc[j]);
#pragma unroll
  for (int j = 0; j < 8; ++j) acc[j] = fmaf(v.w, wk[3*EMB + j], acc[j]);
}

// ---------------- lin_in + p/q via MFMA (one 16-node tile per wave) + fused hist ----------------
// A-frag: m=lane&15 (node), k=(lane>>4)*8+j. B-frag: n=lane&15 (outcol), same k.
// C/D: col=lane&15, row=(lane>>4)*4+reg [m89].
#define HSTRIDE 40  // bf16 LDS tile row stride (16B-aligned, conflict-benign)

__global__ __launch_bounds__(256) void k_lin_in_pq(
    const float* __restrict__ x, const float* __restrict__ w, const float* __restrict__ b,
    const float* __restrict__ w1, const float* __restrict__ b1, const int* __restrict__ ei,
    float* __restrict__ h, unsigned short* __restrict__ p, unsigned short* __restrict__ q,
    int* __restrict__ cnt)
{
  __shared__ __align__(16) unsigned short lds_hb[4][16*HSTRIDE];
  __shared__ __align__(16) unsigned short lds_pq[4][16*HSTRIDE];
  const int lane = threadIdx.x & 63;
  const int wv   = threadIdx.x >> 6;
  const int n0i  = lane & 15;
  const int quad = lane >> 4;

  const int tile = blockIdx.x*4 + wv;
  if (tile < NTILE_N) {
    const int r0 = tile*16;
    // B frags for lin_in W (128x32 f32, row-major) — 4 k-blocks x {lo,hi}
    bf16x8 BwL[4], BwH[4];
#pragma unroll
    for (int kb = 0; kb < 4; ++kb) {
#pragma unroll
      for (int j = 0; j < 8; ++j) {
        const int k = kb*32 + quad*8 + j;
        BwL[kb][j] = (short)f2bf(w[k*EMB + n0i]);
        BwH[kb][j] = (short)f2bf(w[k*EMB + 16 + n0i]);
      }
    }
    f32x4 accL = {0.f,0.f,0.f,0.f};
    f32x4 accH = {0.f,0.f,0.f,0.f};
#pragma unroll
    for (int kb = 0; kb < 4; ++kb) {
      const float4 xa = *(const float4*)(x + (size_t)(r0 + n0i)*IN_DIM + kb*32 + quad*8);
      const float4 xb = *(const float4*)(x + (size_t)(r0 + n0i)*IN_DIM + kb*32 + quad*8 + 4);
      bf16x8 A;
      A[0] = (short)f2bf(xa.x); A[1] = (short)f2bf(xa.y);
      A[2] = (short)f2bf(xa.z); A[3] = (short)f2bf(xa.w);
      A[4] = (short)f2bf(xb.x); A[5] = (short)f2bf(xb.y);
      A[6] = (short)f2bf(xb.z); A[7] = (short)f2bf(xb.w);
      accL = __builtin_amdgcn_mfma_f32_16x16x32_bf16(A, BwL[kb], accL, 0, 0, 0);
      accH = __builtin_amdgcn_mfma_f32_16x16x32_bf16(A, BwH[kb], accH, 0, 0, 0);
    }
    // bias + h store (f32) + LDS stash (bf16) for the p/q matmuls
    const float bL = b[n0i], bH = b[16 + n0i];
#pragma unroll
    for (int r = 0; r < 4; ++r) {
      const int row = quad*4 + r;
      const float vL = accL[r] + bL;
      const float vH = accH[r] + bH;
      h[(size_t)(r0 + row)*EMB + n0i]      = vL;
      h[(size_t)(r0 + row)*EMB + 16 + n0i] = vH;
      lds_hb[wv][row*HSTRIDE + n0i]      = f2bf(vL);
      lds_hb[wv][row*HSTRIDE + 16 + n0i] = f2bf(vH);
    }
    // A2 from LDS (wave-private; DS ops wave-ordered, no barrier)
    bf16x8 A2;
#pragma unroll
    for (int j = 0; j < 8; ++j)
      A2[j] = (short)lds_hb[wv][n0i*HSTRIDE + quad*8 + j];
    // B frags for p (w1 rows 0..31) and q (rows 32..63)
    bf16x8 BpL, BpH, BqL, BqH;
#pragma unroll
    for (int j = 0; j < 8; ++j) {
      const int k = quad*8 + j;
      BpL[j] = (short)f2bf(w1[k*EMB + n0i]);
      BpH[j] = (short)f2bf(w1[k*EMB + 16 + n0i]);
      BqL[j] = (short)f2bf(w1[(EMB + k)*EMB + n0i]);
      BqH[j] = (short)f2bf(w1[(EMB + k)*EMB + 16 + n0i]);
    }
    const f32x4 z4 = {0.f,0.f,0.f,0.f};
    f32x4 pL = __builtin_amdgcn_mfma_f32_16x16x32_bf16(A2, BpL, z4, 0, 0, 0);
    f32x4 pH = __builtin_amdgcn_mfma_f32_16x16x32_bf16(A2, BpH, z4, 0, 0, 0);
    f32x4 qL = __builtin_amdgcn_mfma_f32_16x16x32_bf16(A2, BqL, z4, 0, 0, 0);
    f32x4 qH = __builtin_amdgcn_mfma_f32_16x16x32_bf16(A2, BqH, z4, 0, 0, 0);
    // p: fold b1, repack via LDS, 16B stores
    const float b1L = b1[n0i], b1H = b1[16 + n0i];
#pragma unroll
    for (int r = 0; r < 4; ++r) {
      const int row = quad*4 + r;
      lds_pq[wv][row*HSTRIDE + n0i]      = f2bf(pL[r] + b1L);
      lds_pq[wv][row*HSTRIDE + 16 + n0i] = f2bf(pH[r] + b1H);
    }
    {
      const int row2 = lane >> 2;
      const int c8   = (lane & 3)*8;
      const uint4 ov = *(const uint4*)&lds_pq[wv][row2*HSTRIDE + c8];
      *(uint4*)(p + (size_t)(r0 + row2)*EMB + c8) = ov;
    }
    // q: same tile reused (wave-ordered DS)
#pragma unroll
    for (int r = 0; r < 4; ++r) {
      const int row = quad*4 + r;
      lds_pq[wv][row*HSTRIDE + n0i]      = f2bf(qL[r]);
      lds_pq[wv][row*HSTRIDE + 16 + n0i] = f2bf(qH[r]);
    }
    {
      const int row2 = lane >> 2;
      const int c8   = (lane & 3)*8;
      const uint4 ov = *(const uint4*)&lds_pq[wv][row2*HSTRIDE + c8];
      *(uint4*)(q + (size_t)(r0 + row2)*EMB + c8) = ov;
    }
  }
  // fused histogram
  for (int e = blockIdx.x*256 + threadIdx.x; e < N_EDGES; e += gridDim.x*256)
    atomicAdd(&cnt[ei[N_EDGES + e]], 1);
}

// ---------------- CSR build ----------------
__global__ __launch_bounds__(256) void k_scan_a(const int* __restrict__ cnt,
                                                int* __restrict__ row_ptr, int* __restrict__ bsum) {
  __shared__ int s[256];
  const int gid = blockIdx.x*256 + threadIdx.x;
  const int v = (gid < N_NODES) ? cnt[gid] : 0;
  s[threadIdx.x] = v;
  __syncthreads();
  for (int o = 1; o < 256; o <<= 1) {
    const int t = (threadIdx.x >= o) ? s[threadIdx.x - o] : 0;
    __syncthreads();
    s[threadIdx.x] += t;
    __syncthreads();
  }
  if (gid < N_NODES) row_ptr[gid] = s[threadIdx.x] - v;
  if (threadIdx.x == 255) bsum[blockIdx.x] = s[255];
}

// fused scan_b+c: every block redundantly scans the 196 block sums, adds its offset
__global__ __launch_bounds__(256) void k_scan_bc(int* __restrict__ row_ptr,
                                                 const int* __restrict__ bsum) {
  __shared__ int s[256];
  const int t = threadIdx.x;
  const int v = (t < NODE_GRID) ? bsum[t] : 0;
  s[t] = v;
  __syncthreads();
  for (int o = 1; o < 256; o <<= 1) {
    const int tt = (t >= o) ? s[t - o] : 0;
    __syncthreads();
    s[t] += tt;
    __syncthreads();
  }
  const int off = (blockIdx.x == 0) ? 0 : s[blockIdx.x - 1];
  const int gid = blockIdx.x*256 + t;
  if (gid < N_NODES) row_ptr[gid] += off;
  if (blockIdx.x == 0 && t == 0) row_ptr[N_NODES] = N_EDGES;
}

// fused place + permute: direct scatter of src/dst/ea(bf16) into CSR order
__global__ __launch_bounds__(256) void k_place_scatter(
    const int* __restrict__ ei, const float* __restrict__ ea,
    const int* __restrict__ row_ptr, int* __restrict__ cnt2,
    int* __restrict__ src_perm, int* __restrict__ dst_perm,
    unsigned short* __restrict__ ea_perm)
{
  const int e = blockIdx.x*256 + threadIdx.x;  // grid 3125 exact
  const int d = ei[N_EDGES + e];
  const int pos = row_ptr[d] + atomicAdd(&cnt2[d], 1);
  src_perm[pos] = ei[e];
  dst_perm[pos] = d;
  const float4 v0 = ((const float4*)(ea + (size_t)e*ED))[0];
  const float4 v1 = ((const float4*)(ea + (size_t)e*ED))[1];
  const float ev[8] = {v0.x, v0.y, v0.z, v0.w, v1.x, v1.y, v1.z, v1.w};
  unsigned u[4];
#pragma unroll
  for (int j = 0; j < 4; ++j)
    u[j] = (unsigned)f2bf(ev[2*j]) | ((unsigned)f2bf(ev[2*j+1]) << 16);
  uint4 o; o.x = u[0]; o.y = u[1]; o.z = u[2]; o.w = u[3];
  *(uint4*)(ea_perm + (size_t)pos*ED) = o;
}

// ---------------- edge kernels ----------------

// y1[i] = p[dst] + q[src] + ea[i]@w1b (b1 folded in p); bf16 in/out; stats.
__global__ __launch_bounds__(256) void k_msg1(
    const unsigned short* __restrict__ pb, const unsigned short* __restrict__ qb,
    const int* __restrict__ src_perm, const int* __restrict__ dst_perm,
    const unsigned short* __restrict__ ea_perm,
    const float* __restrict__ w1b,
    unsigned short* __restrict__ y, float* __restrict__ stats)
{
  float ts[EMB], tss[EMB];
#pragma unroll
  for (int c = 0; c < EMB; ++c) { ts[c] = 0.f; tss[c] = 0.f; }
  const int base = blockIdx.x*(256*MSG1_EPT) + threadIdx.x;
  for (int it = 0; it < MSG1_EPT; ++it) {
    const int i = base + it*256;
    if (i >= N_EDGES) break;
    const int dst = dst_perm[i];
    const int src = src_perm[i];
    float acc[EMB];
    const uint4* pd = (const uint4*)(pb + (size_t)dst*EMB);
    const uint4* qs = (const uint4*)(qb + (size_t)src*EMB);
#pragma unroll
    for (int j4 = 0; j4 < 4; ++j4) {
      const uint4 a = pd[j4];
      const uint4 b = qs[j4];
      const unsigned ua[4] = {a.x, a.y, a.z, a.w};
      const unsigned ub[4] = {b.x, b.y, b.z, b.w};
#pragma unroll
      for (int t = 0; t < 4; ++t) {
        acc[j4*8 + 2*t]   = bf2f((unsigned short)(ua[t] & 0xFFFFu)) +
                            bf2f((unsigned short)(ub[t] & 0xFFFFu));
        acc[j4*8 + 2*t+1] = bf2f((unsigned short)(ua[t] >> 16)) +
                            bf2f((unsigned short)(ub[t] >> 16));
      }
    }
    const uint4 eraw = *(const uint4*)(ea_perm + (size_t)i*ED);
    const unsigned ue[4] = {eraw.x, eraw.y, eraw.z, eraw.w};
    float ev[8];
#pragma unroll
    for (int t = 0; t < 4; ++t) {
      ev[2*t]   = bf2f((unsigned short)(ue[t] & 0xFFFFu));
      ev[2*t+1] = bf2f((unsigned short)(ue[t] >> 16));
    }
#pragma unroll
    for (int k = 0; k < 8; ++k) {
      const float* wk = w1b + k*EMB;
#pragma unroll
      for (int c = 0; c < EMB; ++c) acc[c] = fmaf(ev[k], wk[c], acc[c]);
    }
    unsigned short us[EMB];
#pragma unroll
    for (int c = 0; c < EMB; ++c) us[c] = f2bf(acc[c]);
    unsigned u[16];
#pragma unroll
    for (int j = 0; j < 16; ++j)
      u[j] = (unsigned)us[2*j] | ((unsigned)us[2*j+1] << 16);
    uint4* dp = (uint4*)(y + (size_t)i*EMB);
#pragma unroll
    for (int j = 0; j < 4; ++j) {
      uint4 o; o.x = u[4*j]; o.y = u[4*j+1]; o.z = u[4*j+2]; o.w = u[4*j+3];
      dp[j] = o;
    }
#pragma unroll
    for (int c = 0; c < EMB; ++c) {
      const float v = bf2f(us[c]);
      ts[c] += v;
      tss[c] = fmaf(v, v, tss[c]);
    }
  }
  block_stats_atomic(ts, tss, stats);
}

// MFMA msg2: y2 = bf16( relu(bn1(y1)) @ bf16(W2) + b2 ), in place; coef inline; stats.
__global__ __launch_bounds__(256) void k_msg2(
    unsigned short* __restrict__ y,
    const float* __restrict__ stats1, const float* __restrict__ g1, const float* __restrict__ be1,
    const float* __restrict__ w2, const float* __restrict__ b2,
    float* __restrict__ stats2)
{
  __shared__ __align__(16) unsigned short lds_t[4][16*32];
  __shared__ float lds_s[4][32], lds_q[4][32];
  __shared__ float cf[64];

  coef_from_stats(stats1, g1, be1, 1.0f/(float)N_EDGES, cf);

  const int lane = threadIdx.x & 63;
  const int wid  = threadIdx.x >> 6;
  const int n0 = lane & 15;
  const int kb = lane >> 4;

  bf16x8 Blo, Bhi;
#pragma unroll
  for (int j = 0; j < 8; ++j) {
    Blo[j] = (short)f2bf(w2[(kb*8 + j)*EMB + n0]);
    Bhi[j] = (short)f2bf(w2[(kb*8 + j)*EMB + 16 + n0]);
  }
  float a1[8], c1[8];
#pragma unroll
  for (int j = 0; j < 8; ++j) {
    a1[j] = cf[kb*8 + j];
    c1[j] = cf[EMB + kb*8 + j];
  }
  const float b2c0 = b2[n0], b2c1 = b2[16 + n0];

  float ts[8], tss[8];
#pragma unroll
  for (int j = 0; j < 8; ++j) { ts[j] = 0.f; tss[j] = 0.f; }

  const int tile0 = blockIdx.x * (MSG2_TPW*4);
  for (int t = 0; t < MSG2_TPW; ++t) {
    const int tile = tile0 + t*4 + wid;
    if (tile >= NT16) break;
    const size_t e0 = (size_t)tile * 16;

    const uint4 araw = *(const uint4*)(y + (e0 + n0)*EMB + kb*8);
    unsigned int ua[4] = {araw.x, araw.y, araw.z, araw.w};
    bf16x8 A;
#pragma unroll
    for (int j = 0; j < 4; ++j) {
      float v0 = bf2f((unsigned short)(ua[j] & 0xFFFFu));
      float v1 = bf2f((unsigned short)(ua[j] >> 16));
      v0 = fmaxf(fmaf(a1[2*j],   v0, c1[2*j]),   0.f);
      v1 = fmaxf(fmaf(a1[2*j+1], v1, c1[2*j+1]), 0.f);
      A[2*j]   = (short)f2bf(v0);
      A[2*j+1] = (short)f2bf(v1);
    }

    f32x4 acc0 = {0.f, 0.f, 0.f, 0.f};
    f32x4 acc1 = {0.f, 0.f, 0.f, 0.f};
    acc0 = __builtin_amdgcn_mfma_f32_16x16x32_bf16(A, Blo, acc0, 0, 0, 0);
    acc1 = __builtin_amdgcn_mfma_f32_16x16x32_bf16(A, Bhi, acc1, 0, 0, 0);

#pragma unroll
    for (int r = 0; r < 4; ++r) {
      const int row = kb*4 + r;
      lds_t[wid][row*32 + n0]      = f2bf(acc0[r] + b2c0);
      lds_t[wid][row*32 + 16 + n0] = f2bf(acc1[r] + b2c1);
    }
    const uint4 orow = *(const uint4*)&lds_t[wid][(lane>>2)*32 + (lane&3)*8];
    *(uint4*)(y + (e0 + (lane>>2))*EMB + (lane&3)*8) = orow;

    unsigned int uo[4] = {orow.x, orow.y, orow.z, orow.w};
#pragma unroll
    for (int j = 0; j < 4; ++j) {
      const float v0 = bf2f((unsigned short)(uo[j] & 0xFFFFu));
      const float v1 = bf2f((unsigned short)(uo[j] >> 16));
      ts[2*j]   += v0;  tss[2*j]   = fmaf(v0, v0, tss[2*j]);
      ts[2*j+1] += v1;  tss[2*j+1] = fmaf(v1, v1, tss[2*j+1]);
    }
  }

#pragma unroll
  for (int j = 0; j < 8; ++j) {
    float s = ts[j], qq = tss[j];
#pragma unroll
    for (int o = 4; o < 64; o <<= 1) {
      s  += __shfl_xor(s, o, 64);
      qq += __shfl_xor(qq, o, 64);
    }
    ts[j] = s; tss[j] = qq;
  }
  if (lane < 4) {
#pragma unroll
    for (int j = 0; j < 8; ++j) {
      lds_s[wid][lane*8 + j] = ts[j];
      lds_q[wid][lane*8 + j] = tss[j];
    }
  }
  __syncthreads();
  if (threadIdx.x < 64) {
    const int c = threadIdx.x & 31;
    const int kind = threadIdx.x >> 5;
    float v = 0.f;
#pragma unroll
    for (int wq = 0; wq < 4; ++wq)
      v += kind ? lds_q[wq][c] : lds_s[wq][c];
    atomicAdd(stats2 + ((blockIdx.x & (SREP-1)) << 6) + kind*32 + c, v);
  }
}

// fused aggr + upd1: aggr lives in LDS only; z1 = concat(h,aggr)@uw1+b; stats.
__global__ __launch_bounds__(256) void k_aggr_upd1(
    const unsigned short* __restrict__ y, const int* __restrict__ row_ptr,
    const float* __restrict__ h,
    const float* __restrict__ stats1, const float* __restrict__ g2, const float* __restrict__ be2,
    const float* __restrict__ uw1, const float* __restrict__ ub1,
    float* __restrict__ z, float* __restrict__ stats2)
{
  __shared__ float cf[64];
  __shared__ float lh[8][32];
  __shared__ float la[8][32];
  __shared__ float rs[4][32], rq[4][32];
  coef_from_stats(stats1, g2, be2, 1.0f/(float)N_EDGES, cf);

  const int g = threadIdx.x >> 5;
  const int l = threadIdx.x & 31;
  const int n = blockIdx.x*8 + g;   // grid 6250 exact -> n < N_NODES always

  // stage h row into LDS (coalesced)
  lh[g][l] = h[(size_t)n*EMB + l];

  // aggregation (2 cols/lane, 2 rows/iter)
  const int rof = l >> 4;
  const int cp  = l & 15;
  const float a0 = cf[2*cp],     b0 = cf[EMB + 2*cp];
  const float a1 = cf[2*cp + 1], b1 = cf[EMB + 2*cp + 1];
  const int lo = row_ptr[n], hi = row_ptr[n+1];
  float s0 = 0.f, s1 = 0.f;
  for (int i = lo + rof; i < hi; i += 2) {
    const unsigned u = *(const unsigned*)(y + (size_t)i*EMB + 2*cp);
    const float v0 = bf2f((unsigned short)(u & 0xFFFFu));
    const float v1 = bf2f((unsigned short)(u >> 16));
    s0 += fmaxf(fmaf(a0, v0, b0), 0.f);
    s1 += fmaxf(fmaf(a1, v1, b1), 0.f);
  }
  s0 += __shfl_xor(s0, 16, 64);
  s1 += __shfl_xor(s1, 16, 64);
  if (rof == 0) { la[g][2*cp] = s0; la[g][2*cp + 1] = s1; }
  __syncthreads();

  // upd1: col l of node n
  float acc = ub1[l];
#pragma unroll
  for (int k = 0; k < EMB; ++k) acc = fmaf(lh[g][k], uw1[k*EMB + l], acc);
#pragma unroll
  for (int k = 0; k < EMB; ++k) acc = fmaf(la[g][k], uw1[(EMB + k)*EMB + l], acc);
  z[(size_t)n*EMB + l] = acc;

  // stats
  const float sq = acc*acc;
  const float a2 = acc + __shfl_down(acc, 32, 64);
  const float q2 = sq  + __shfl_down(sq,  32, 64);
  const int wv = threadIdx.x >> 6;
  if ((threadIdx.x & 63) < 32) { rs[wv][l] = a2; rq[wv][l] = q2; }
  __syncthreads();
  if (threadIdx.x < 64) {
    const int c = threadIdx.x & 31;
    const int kind = threadIdx.x >> 5;
    float v = 0.f;
#pragma unroll
    for (int wq = 0; wq < 4; ++wq)
      v += kind ? rq[wq][c] : rs[wq][c];
    atomicAdd(stats2 + ((blockIdx.x & (SREP-1)) << 6) + kind*32 + c, v);
  }
}

// z2 = relu(bn(z1)) @ uw2 + b, in place on z; coef inline; stats. (4-wave col-split)
__global__ __launch_bounds__(256) void k_upd2(
    float* __restrict__ z,
    const float* __restrict__ stats1, const float* __restrict__ g1, const float* __restrict__ be1,
    const float* __restrict__ w, const float* __restrict__ b,
    float* __restrict__ stats2)
{
  __shared__ float cf[64];
  __shared__ float lds_s[32], lds_q[32];
  coef_from_stats(stats1, g1, be1, 1.0f/(float)N_NODES, cf);

  const int lane = threadIdx.x & 63;
  const int wv   = threadIdx.x >> 6;
  const int n  = blockIdx.x*64 + lane;
  const int c0 = wv*8;
  float acc[8];
#pragma unroll
  for (int j = 0; j < 8; ++j) acc[j] = 0.f;
  if (n < N_NODES) {
#pragma unroll
    for (int j = 0; j < 8; ++j) acc[j] = b[c0 + j];
    const float4* zp = (const float4*)(z + (size_t)n*EMB);
#pragma unroll
    for (int k4 = 0; k4 < 8; ++k4) {
      const float4 v = zp[k4];
      const float mv[4] = {v.x, v.y, v.z, v.w};
#pragma unroll
      for (int t = 0; t < 4; ++t) {
        const int k = 4*k4 + t;
        const float m = fmaxf(fmaf(cf[k], mv[t], cf[EMB + k]), 0.f);
        const float* wk = w + k*EMB + c0;
#pragma unroll
        for (int j = 0; j < 8; ++j) acc[j] = fmaf(m, wk[j], acc[j]);
      }
    }
  }
  float ts[8], tss[8];
#pragma unroll
  for (int j = 0; j < 8; ++j) { ts[j] = acc[j]; tss[j] = acc[j]*acc[j]; }
  wave_stats_atomic(ts, tss, lds_s, lds_q, stats2);  // barrier inside
  if (n < N_NODES) {
    float4 o0, o1;
    o0.x = acc[0]; o0.y = acc[1]; o0.z = acc[2]; o0.w = acc[3];
    o1.x = acc[4]; o1.y = acc[5]; o1.z = acc[6]; o1.w = acc[7];
    *(float4*)(z + (size_t)n*EMB + c0)     = o0;
    *(float4*)(z + (size_t)n*EMB + c0 + 4) = o1;
  }
}

// h += relu(bn(z2)); p/q (bf16, b1_next folded into p) via LDS hn-exchange.
__global__ __launch_bounds__(256) void k_resid_pq(
    float* __restrict__ h, const float* __restrict__ z,
    const float* __restrict__ stats, const float* __restrict__ g, const float* __restrict__ be,
    const float* __restrict__ w1_next, const float* __restrict__ b1_next,
    unsigned short* __restrict__ p, unsigned short* __restrict__ q)
{
  __shared__ float cf[64];
  __shared__ float lds_h[64][33];
  coef_from_stats(stats, g, be, 1.0f/(float)N_NODES, cf);

  const int lane = threadIdx.x & 63;
  const int wv   = threadIdx.x >> 6;
  const int n  = blockIdx.x*64 + lane;
  const int c0 = wv*8;
  if (n < N_NODES) {
    const float4* zp = (const float4*)(z + (size_t)n*EMB + c0);
    float4* hp = (float4*)(h + (size_t)n*EMB + c0);
    float hn[8];
    const float4 z0 = zp[0], z1 = zp[1];
    const float4 h0 = hp[0], h1 = hp[1];
    const float zv[8] = {z0.x, z0.y, z0.z, z0.w, z1.x, z1.y, z1.z, z1.w};
    const float hv[8] = {h0.x, h0.y, h0.z, h0.w, h1.x, h1.y, h1.z, h1.w};
#pragma unroll
    for (int j = 0; j < 8; ++j) {
      const int k = c0 + j;
      hn[j] = hv[j] + fmaxf(fmaf(cf[k], zv[j], cf[EMB + k]), 0.f);
      lds_h[lane][k] = hn[j];
    }
    float4 o0, o1;
    o0.x = hn[0]; o0.y = hn[1]; o0.z = hn[2]; o0.w = hn[3];
    o1.x = hn[4]; o1.y = hn[5]; o1.z = hn[6]; o1.w = hn[7];
    hp[0] = o0; hp[1] = o1;
  }
  __syncthreads();
  if (n < N_NODES && w1_next) {
    float ap[8], aq[8];
#pragma unroll
    for (int j = 0; j < 8; ++j) { ap[j] = b1_next[c0 + j]; aq[j] = 0.f; }
#pragma unroll
    for (int k = 0; k < EMB; ++k) {
      const float hvv = lds_h[lane][k];
      const float* wp = w1_next + k*EMB + c0;
      const float* wq = w1_next + (EMB + k)*EMB + c0;
#pragma unroll
      for (int j = 0; j < 8; ++j) ap[j] = fmaf(hvv, wp[j], ap[j]);
#pragma unroll
      for (int j = 0; j < 8; ++j) aq[j] = fmaf(hvv, wq[j], aq[j]);
    }
    unsigned up[4], uq[4];
#pragma unroll
    for (int j = 0; j < 4; ++j) {
      up[j] = (unsigned)f2bf(ap[2*j]) | ((unsigned)f2bf(ap[2*j+1]) << 16);
      uq[j] = (unsigned)f2bf(aq[2*j]) | ((unsigned)f2bf(aq[2*j+1]) << 16);
    }
    uint4 op; op.x = up[0]; op.y = up[1]; op.z = up[2]; op.w = up[3];
    uint4 oq; oq.x = uq[0]; oq.y = uq[1]; oq.z = uq[2]; oq.w = uq[3];
    *(uint4*)(p + (size_t)n*EMB + c0) = op;
    *(uint4*)(q + (size_t)n*EMB + c0) = oq;
  }
}

// per-graph mean pool + final linear
__global__ void k_pool(const float* __restrict__ h, const int* __restrict__ batch,
                       const float* __restrict__ pw, const float* __restrict__ pb,
                       float* __restrict__ out)
{
  __shared__ float sred[256];
  __shared__ float hg[EMB];
  const int b = blockIdx.x;
  int lo = 0, hi = N_NODES;
  while (lo < hi) { int m = (lo + hi) >> 1; if (batch[m] < b) lo = m + 1; else hi = m; }
  const int start = lo;
  hi = N_NODES;
  while (lo < hi) { int m = (lo + hi) >> 1; if (batch[m] < b + 1) lo = m + 1; else hi = m; }
  const int end = lo;

  const int c = threadIdx.x & (EMB-1);
  const int r = threadIdx.x >> 5;
  float s = 0.f;
  for (int n = start + r; n < end; n += 8) s += h[(size_t)n*EMB + c];
  sred[threadIdx.x] = s;
  __syncthreads();
  if (threadIdx.x < EMB) {
    float tot = 0.f;
#pragma unroll
    for (int r2 = 0; r2 < 8; ++r2) tot += sred[r2*EMB + threadIdx.x];
    const float cnt = (float)(end - start);
    hg[threadIdx.x] = tot / fmaxf(cnt, 1.f);
  }
  __syncthreads();
  if (threadIdx.x < OUTD) {
    float acc = pb[threadIdx.x];
#pragma unroll
    for (int cc = 0; cc < EMB; ++cc) acc = fmaf(hg[cc], pw[cc*OUTD + threadIdx.x], acc);
    out[b*OUTD + threadIdx.x] = acc;
  }
}

// ---------------- host ----------------

extern "C" void kernel_launch(void* const* d_in, const int* in_sizes, int n_in,
                              void* d_out, int out_size, void* d_ws, size_t ws_size,
                              hipStream_t stream) {
  const float* x        = (const float*)d_in[0];
  const int*   ei       = (const int*)  d_in[1];
  const float* ea       = (const float*)d_in[2];
  const int*   batch    = (const int*)  d_in[3];
  const float* lin_in_w = (const float*)d_in[4];
  const float* lin_in_b = (const float*)d_in[5];
  const float* msg_w1   = (const float*)d_in[6];
  const float* msg_b1   = (const float*)d_in[7];
  const float* msg_g1   = (const float*)d_in[8];
  const float* msg_be1  = (const float*)d_in[9];
  const float* msg_w2   = (const float*)d_in[10];
  const float* msg_b2   = (const float*)d_in[11];
  const float* msg_g2   = (const float*)d_in[12];
  const float* msg_be2  = (const float*)d_in[13];
  const float* upd_w1   = (const float*)d_in[14];
  const float* upd_b1   = (const float*)d_in[15];
  const float* upd_g1   = (const float*)d_in[16];
  const float* upd_be1  = (const float*)d_in[17];
  const float* upd_w2   = (const float*)d_in[18];
  const float* upd_b2   = (const float*)d_in[19];
  const float* upd_g2   = (const float*)d_in[20];
  const float* upd_be2  = (const float*)d_in[21];
  const float* pred_w   = (const float*)d_in[22];
  const float* pred_b   = (const float*)d_in[23];
  float* out = (float*)d_out;

  // Workspace layout (~90 MB)
  char* wsb = (char*)d_ws;
  unsigned short* y  = (unsigned short*)wsb;                            // E*32 bf16
  unsigned short* eap= (unsigned short*)(wsb + (size_t)N_EDGES*EMB*2);  // E*8 bf16
  unsigned short* p  = eap + (size_t)N_EDGES*ED;                        // N*32 bf16
  unsigned short* q  = p + (size_t)N_NODES*EMB;                         // N*32 bf16
  float* h       = (float*)(q + (size_t)N_NODES*EMB);                   // N*32 f32
  float* z       = h + (size_t)N_NODES*EMB;                             // N*32 f32 (z1/z2 in place)
  float* stats   = z + (size_t)N_NODES*EMB;                             // 16 x SREP x 64
  int*   cnt     = (int*)(stats + 16*SREP*64);
  int*   cnt2    = cnt + N_NODES;
  int*   row_ptr = cnt2 + N_NODES;
  int*   bsum    = row_ptr + N_NODES + 1;
  int*   src_perm= bsum + 256;
  int*   dst_perm= src_perm + N_EDGES;
  const size_t need = ((size_t)((char*)(dst_perm + N_EDGES) - wsb));
  if (ws_size < need) return;

  hipMemsetAsync(stats, 0, (16*SREP*64 + 2*N_NODES)*sizeof(float), stream);

  k_lin_in_pq<<<LIN_GRID, 256, 0, stream>>>(x, lin_in_w, lin_in_b, msg_w1, msg_b1, ei,
                                            h, p, q, cnt);
  k_scan_a<<<NODE_GRID, 256, 0, stream>>>(cnt, row_ptr, bsum);
  k_scan_bc<<<NODE_GRID, 256, 0, stream>>>(row_ptr, bsum);
  k_place_scatter<<<EDGE_GRID, 256, 0, stream>>>(ei, ea, row_ptr, cnt2,
                                                 src_perm, dst_perm, eap);

  for (int l = 0; l < NLAYERS; ++l) {
    const int st = l*4;
    const float* w1  = msg_w1 + (size_t)l*(2*EMB+ED)*EMB;
    const float* w1b = w1 + (size_t)2*EMB*EMB;
    const float* w2  = msg_w2 + (size_t)l*EMB*EMB;
    const float* uw1 = upd_w1 + (size_t)l*(2*EMB)*EMB;
    const float* uw2 = upd_w2 + (size_t)l*EMB*EMB;
    const float* w1_next = (l+1 < NLAYERS) ? msg_w1 + (size_t)(l+1)*(2*EMB+ED)*EMB : nullptr;
    const float* b1_next = (l+1 < NLAYERS) ? msg_b1 + (size_t)(l+1)*EMB : nullptr;

    k_msg1<<<MSG1_GRID, 256, 0, stream>>>(p, q, src_perm, dst_perm, eap,
                                          w1b, y, stats + (size_t)st*SREP*64);
    k_msg2<<<MSG2_GRID, 256, 0, stream>>>(y, stats + (size_t)st*SREP*64,
                                          msg_g1 + l*EMB, msg_be1 + l*EMB,
                                          w2, msg_b2 + l*EMB, stats + (size_t)(st+1)*SREP*64);
    k_aggr_upd1<<<AU_GRID, 256, 0, stream>>>(y, row_ptr, h,
                                             stats + (size_t)(st+1)*SREP*64,
                                             msg_g2 + l*EMB, msg_be2 + l*EMB,
                                             uw1, upd_b1 + l*EMB,
                                             z, stats + (size_t)(st+2)*SREP*64);
    k_upd2<<<NODE4_GRID, 256, 0, stream>>>(z, stats + (size_t)(st+2)*SREP*64,
                                           upd_g1 + l*EMB, upd_be1 + l*EMB,
                                           uw2, upd_b2 + l*EMB, stats + (size_t)(st+3)*SREP*64);
    k_resid_pq<<<NODE4_GRID, 256, 0, stream>>>(h, z, stats + (size_t)(st+3)*SREP*64,
                                               upd_g2 + l*EMB, upd_be2 + l*EMB,
                                               w1_next, b1_next, p, q);
  }

  k_pool<<<NB, 256, 0, stream>>>(h, batch, pred_w, pred_b, out);
}